// Round 12
// baseline (318.210 us; speedup 1.0000x reference)
//
#include <hip/hip_runtime.h>
#include <hip/hip_bf16.h>

typedef float f32x4 __attribute__((ext_vector_type(4)));
typedef short bf16x8 __attribute__((ext_vector_type(8)));

#define HH 512
#define WW 512
#define NPLANES 48              // B*C = 16*3
#define KSIZE 23
#define NBLK (16 * 16 * NPLANES)
#define C1V 1.0e-4f             // 0.01^2
#define C2V 9.0e-4f             // 0.03^2

// LDS (ushort indices): G[32][64] + hb[5][32 cols][64 rows], both xor-swizzled.
// Frame: col/row k of the tile = image col/row (tile*32 - 12 + k).
// G[r][k] = g[k-1-r] for k-1-r in [0,23) else 0  => used k-range [1,55).
// Frame rows {0} u [55,64) are written-but-junk; they hit exact G zeros.
#define G_O    0                // 2048 ushorts
#define HB_O   2048             // 5 * 2048
#define HB_CH  2048
#define LDS_TOT 12288           // 24576 B -> 6 blocks/CU

// XOR bank swizzle for pitch-64 regions; preserves 16B blocks (bits 0..2).
#define SWZ(rho, k) ((k) ^ (((rho) & 7) << 3))

__device__ __forceinline__ unsigned f2bf(float x) {   // fp32 -> bf16 bits (RNE)
    unsigned u = __float_as_uint(x);
    return (u + 0x7fffu + ((u >> 16) & 1u)) >> 16;
}

// pack two fp32 -> bf16 pair (lo = a, hi = b), RNE (v_cvt_pk_bf16_f32)
__device__ __forceinline__ unsigned cvtpk(float a, float b) {
    union { __hip_bfloat162 h; unsigned u; } cv;
    cv.h = __float22bfloat162_rn(make_float2(a, b));
    return cv.u;
}

__device__ __forceinline__ f32x4 mfma16(uint4 a, uint4 b, f32x4 c) {
    union { uint4 u; bf16x8 h; } ua, ub;
    ua.u = a; ub.u = b;
    return __builtin_amdgcn_mfma_f32_16x16x32_bf16(ua.h, ub.h, c, 0, 0, 0);
}

__global__ __launch_bounds__(256, 6) void ssim_main_kernel(
    const float* __restrict__ in, const float* __restrict__ tg,
    const float* __restrict__ w, float* __restrict__ partial)
{
    __shared__ __align__(16) unsigned short lds[LDS_TOT];
    __shared__ float sg[KSIZE];
    __shared__ float swsum[4];

    const int tid = threadIdx.x;
    const int wave = tid >> 6, lane = tid & 63;
    const int m = lane & 15, q = lane >> 4;

    const int blk = blockIdx.x;
    const int plane = blk >> 8;
    const int t2 = blk & 255;
    const int x0 = (t2 & 15) * 32 - 12;   // 12-left halo => 16B-aligned rows
    const int y0 = (t2 >> 4) * 32 - 12;
    const float* __restrict__ inp = in + (size_t)plane * (HH * WW);
    const float* __restrict__ tgp = tg + (size_t)plane * (HH * WW);

    // ---- 1D taps = row sums of separable normalized 2D kernel (exact) ----
    if (tid < KSIZE) {
        float s = 0.f;
        #pragma unroll
        for (int k = 0; k < KSIZE; ++k) s += w[tid * KSIZE + k];
        sg[tid] = s;
    }
    __syncthreads();

    // ---- build G[32][64] in LDS (swizzled): G[r][k] = g[k-1-r] or 0 ----
    for (int t = tid; t < 32 * 64; t += 256) {
        int r = t >> 6, k = t & 63, d = k - 1 - r;
        unsigned short v = 0;
        if ((unsigned)d < (unsigned)KSIZE) v = (unsigned short)f2bf(sg[d]);
        lds[G_O + r * 64 + SWZ(r, k)] = v;
    }
    __syncthreads();

    // ---- h-pass (MFMA): A-fragments loaded DIRECTLY from global ----
    // Lane (m,q), wave w: frame row = w*16+m, frame cols ks*32+q*8 .. +7.
    const bool interior = (x0 >= 0) && (y0 >= 0) && (x0 + 64 <= WW) && (y0 + 64 <= HH);
    const int gy = y0 + wave * 16 + m;

    f32x4 acc5[5][2];
    const f32x4 zz = {0.f, 0.f, 0.f, 0.f};
    #pragma unroll
    for (int ch = 0; ch < 5; ++ch) { acc5[ch][0] = zz; acc5[ch][1] = zz; }

    #pragma unroll
    for (int ks = 0; ks < 2; ++ks) {
        const int cx = x0 + ks * 32 + q * 8;
        float a[8], b[8];
        if (interior) {
            const float* pa = inp + gy * WW + cx;   // 16B-aligned (x0 = 32tx-12)
            const float* pb = tgp + gy * WW + cx;
            float4 va0 = ((const float4*)pa)[0], va1 = ((const float4*)pa)[1];
            float4 vb0 = ((const float4*)pb)[0], vb1 = ((const float4*)pb)[1];
            a[0] = va0.x; a[1] = va0.y; a[2] = va0.z; a[3] = va0.w;
            a[4] = va1.x; a[5] = va1.y; a[6] = va1.z; a[7] = va1.w;
            b[0] = vb0.x; b[1] = vb0.y; b[2] = vb0.z; b[3] = vb0.w;
            b[4] = vb1.x; b[5] = vb1.y; b[6] = vb1.z; b[7] = vb1.w;
        } else {
            const int  gyc = min(max(gy, 0), HH - 1);
            const bool oky = ((unsigned)gy < (unsigned)HH);
            const float* ra = inp + gyc * WW;
            const float* rb = tgp + gyc * WW;
            #pragma unroll
            for (int i = 0; i < 8; ++i) {
                int gx = cx + i;
                int gxc = min(max(gx, 0), WW - 1);
                bool ok = oky && ((unsigned)gx < (unsigned)WW);
                float va = ra[gxc], vb = rb[gxc];
                a[i] = ok ? va : 0.f;
                b[i] = ok ? vb : 0.f;
            }
        }
        uint4 ua, ub, uaa, ubb, uab;
        ua.x  = cvtpk(a[0], a[1]);           ua.y  = cvtpk(a[2], a[3]);
        ua.z  = cvtpk(a[4], a[5]);           ua.w  = cvtpk(a[6], a[7]);
        ub.x  = cvtpk(b[0], b[1]);           ub.y  = cvtpk(b[2], b[3]);
        ub.z  = cvtpk(b[4], b[5]);           ub.w  = cvtpk(b[6], b[7]);
        uaa.x = cvtpk(a[0]*a[0], a[1]*a[1]); uaa.y = cvtpk(a[2]*a[2], a[3]*a[3]);
        uaa.z = cvtpk(a[4]*a[4], a[5]*a[5]); uaa.w = cvtpk(a[6]*a[6], a[7]*a[7]);
        ubb.x = cvtpk(b[0]*b[0], b[1]*b[1]); ubb.y = cvtpk(b[2]*b[2], b[3]*b[3]);
        ubb.z = cvtpk(b[4]*b[4], b[5]*b[5]); ubb.w = cvtpk(b[6]*b[6], b[7]*b[7]);
        uab.x = cvtpk(a[0]*b[0], a[1]*b[1]); uab.y = cvtpk(a[2]*b[2], a[3]*b[3]);
        uab.z = cvtpk(a[4]*b[4], a[5]*b[5]); uab.w = cvtpk(a[6]*b[6], a[7]*b[7]);

        #pragma unroll
        for (int nc = 0; nc < 2; ++nc) {
            const int gr = nc * 16 + m;
            uint4 gf = *(const uint4*)&lds[G_O + gr * 64 + SWZ(gr, ks * 32 + q * 8)];
            acc5[0][nc] = mfma16(ua,  gf, acc5[0][nc]);
            acc5[1][nc] = mfma16(ub,  gf, acc5[1][nc]);
            acc5[2][nc] = mfma16(uaa, gf, acc5[2][nc]);
            acc5[3][nc] = mfma16(ubb, gf, acc5[3][nc]);
            acc5[4][nc] = mfma16(uab, gf, acc5[4][nc]);
        }
    }
    // D frag: col = lane&15 (+nc*16), row = q*4 + reg (+wave*16). hbT[ch][col][row], bf16.
    // Waves 0..3 cover rows 0..63 => every hb row is written (finite junk on 0,55..63).
    #pragma unroll
    for (int ch = 0; ch < 5; ++ch)
        #pragma unroll
        for (int nc = 0; nc < 2; ++nc) {
            f32x4 a = acc5[ch][nc];
            uint2 pk;
            pk.x = cvtpk(a[0], a[1]);
            pk.y = cvtpk(a[2], a[3]);
            const int col = nc * 16 + m;
            const int rb = wave * 16 + q * 4;
            *(uint2*)&lds[HB_O + ch * HB_CH + col * 64 + SWZ(col, rb)] = pk;
        }
    __syncthreads();

    // ---- v-pass (MFMA): wave = output quadrant (mrow, nc2) ----
    // out[r][c] = sum_k G[r][k] * hb[k][c]; junk hb rows hit G zeros.
    const int mrow = wave >> 1, nc2 = wave & 1;
    f32x4 av[5];
    #pragma unroll
    for (int ch = 0; ch < 5; ++ch) av[ch] = zz;

    #pragma unroll
    for (int ks = 0; ks < 2; ++ks) {
        const int ar = mrow * 16 + m;
        uint4 ga = *(const uint4*)&lds[G_O + ar * 64 + SWZ(ar, ks * 32 + q * 8)];
        #pragma unroll
        for (int ch = 0; ch < 5; ++ch) {
            const int col = nc2 * 16 + m;
            uint4 ub = *(const uint4*)&lds[HB_O + ch * HB_CH + col * 64 + SWZ(col, ks * 32 + q * 8)];
            av[ch] = mfma16(ga, ub, av[ch]);
        }
    }

    // ---- SSIM map on 4 px/lane + reduction ----
    float lsum = 0.f;
    #pragma unroll
    for (int i = 0; i < 4; ++i) {
        float vx = av[0][i], vt = av[1][i];
        float vxx = av[2][i], vtt = av[3][i], vxt = av[4][i];
        float m1s = vx * vx, m2s = vt * vt, m12 = vx * vt;
        float s1 = vxx - m1s, s2 = vtt - m2s, s12 = vxt - m12;
        float num = (2.f * m12 + C1V) * (2.f * s12 + C2V);
        float den = (m1s + m2s + C1V) * (s1 + s2 + C2V);
        lsum += num * __builtin_amdgcn_rcpf(den);   // den > 0 always
    }
    #pragma unroll
    for (int off = 32; off > 0; off >>= 1)
        lsum += __shfl_down(lsum, off, 64);
    if (lane == 0) swsum[wave] = lsum;
    __syncthreads();
    if (tid == 0)
        partial[blk] = swsum[0] + swsum[1] + swsum[2] + swsum[3];  // plain store
}

__global__ __launch_bounds__(256) void ssim_final_kernel(
    const float* __restrict__ partial, float* __restrict__ out)
{
    __shared__ float swsum[4];
    const int tid = threadIdx.x;
    float s = 0.f;
    const float4* p4 = (const float4*)partial;
    for (int i = tid; i < NBLK / 4; i += 256) {
        float4 v = p4[i];
        s += (v.x + v.y) + (v.z + v.w);
    }
    #pragma unroll
    for (int off = 32; off > 0; off >>= 1)
        s += __shfl_down(s, off, 64);
    if ((tid & 63) == 0) swsum[tid >> 6] = s;
    __syncthreads();
    if (tid == 0)
        out[0] = 1.0f - (swsum[0] + swsum[1] + swsum[2] + swsum[3])
                        * (1.0f / ((float)NPLANES * HH * WW));
}

extern "C" void kernel_launch(void* const* d_in, const int* in_sizes, int n_in,
                              void* d_out, int out_size, void* d_ws, size_t ws_size,
                              hipStream_t stream) {
    const float* inp = (const float*)d_in[0];
    const float* tgt = (const float*)d_in[1];
    const float* wgt = (const float*)d_in[2];
    float* out = (float*)d_out;
    float* partial = (float*)d_ws;     // NBLK floats, fully overwritten each call

    ssim_main_kernel<<<NBLK, 256, 0, stream>>>(inp, tgt, wgt, partial);
    ssim_final_kernel<<<1, 256, 0, stream>>>(partial, out);
}

// Round 13
// 269.392 us; speedup vs baseline: 1.1812x; 1.1812x over previous
//
#include <hip/hip_runtime.h>
#include <hip/hip_bf16.h>

typedef float f32x4 __attribute__((ext_vector_type(4)));
typedef short bf16x8 __attribute__((ext_vector_type(8)));

#define HH 512
#define WW 512
#define NPLANES 48              // B*C = 16*3
#define KSIZE 23
#define NBLK (16 * 16 * NPLANES)
#define C1V 1.0e-4f             // 0.01^2
#define C2V 9.0e-4f             // 0.03^2

// LDS (ushort indices): G[32][64] + hb[5][32 cols][64 rows], both xor-swizzled.
// Frame: col/row k of the tile = image col/row (tile*32 - 12 + k).
// G[r][k] = g[k-1-r] for k-1-r in [0,23) else 0  => used k-range [1,55).
// Frame rows {0} u [55,64) are written-but-junk; they hit exact G zeros.
#define G_O    0                // 2048 ushorts
#define HB_O   2048             // 5 * 2048
#define HB_CH  2048
#define LDS_TOT 12288           // 24576 B

// XOR bank swizzle for pitch-64 regions; preserves 16B blocks (bits 0..2).
#define SWZ(rho, k) ((k) ^ (((rho) & 7) << 3))

__device__ __forceinline__ unsigned f2bf(float x) {   // fp32 -> bf16 bits (RNE)
    unsigned u = __float_as_uint(x);
    return (u + 0x7fffu + ((u >> 16) & 1u)) >> 16;
}

// pack two fp32 -> bf16 pair (lo = a, hi = b), RNE (v_cvt_pk_bf16_f32)
__device__ __forceinline__ unsigned cvtpk(float a, float b) {
    union { __hip_bfloat162 h; unsigned u; } cv;
    cv.h = __float22bfloat162_rn(make_float2(a, b));
    return cv.u;
}

__device__ __forceinline__ f32x4 mfma16(uint4 a, uint4 b, f32x4 c) {
    union { uint4 u; bf16x8 h; } ua, ub;
    ua.u = a; ub.u = b;
    return __builtin_amdgcn_mfma_f32_16x16x32_bf16(ua.h, ub.h, c, 0, 0, 0);
}

// launch_bounds (256,4): VGPR cap 128 >= ~95-reg live set. (256,6) capped at
// ~85 and spilled 189 MB to scratch (round-12 post-mortem) — do not raise.
__global__ __launch_bounds__(256, 4) void ssim_main_kernel(
    const float* __restrict__ in, const float* __restrict__ tg,
    const float* __restrict__ w, float* __restrict__ partial)
{
    __shared__ __align__(16) unsigned short lds[LDS_TOT];
    __shared__ float sg[KSIZE];
    __shared__ float swsum[4];

    const int tid = threadIdx.x;
    const int wave = tid >> 6, lane = tid & 63;
    const int m = lane & 15, q = lane >> 4;

    const int blk = blockIdx.x;
    const int plane = blk >> 8;
    const int t2 = blk & 255;
    const int x0 = (t2 & 15) * 32 - 12;   // 12-left halo => 16B-aligned rows
    const int y0 = (t2 >> 4) * 32 - 12;
    const float* __restrict__ inp = in + (size_t)plane * (HH * WW);
    const float* __restrict__ tgp = tg + (size_t)plane * (HH * WW);

    // ---- 1D taps = row sums of separable normalized 2D kernel (exact) ----
    if (tid < KSIZE) {
        float s = 0.f;
        #pragma unroll
        for (int k = 0; k < KSIZE; ++k) s += w[tid * KSIZE + k];
        sg[tid] = s;
    }
    __syncthreads();

    // ---- build G[32][64] in LDS (swizzled): G[r][k] = g[k-1-r] or 0 ----
    for (int t = tid; t < 32 * 64; t += 256) {
        int r = t >> 6, k = t & 63, d = k - 1 - r;
        unsigned short v = 0;
        if ((unsigned)d < (unsigned)KSIZE) v = (unsigned short)f2bf(sg[d]);
        lds[G_O + r * 64 + SWZ(r, k)] = v;
    }
    __syncthreads();

    // ---- h-pass (MFMA): A-fragments loaded DIRECTLY from global ----
    // Lane (m,q), wave w: frame row = w*16+m, frame cols ks*32+q*8 .. +7.
    const bool interior = (x0 >= 0) && (y0 >= 0) && (x0 + 64 <= WW) && (y0 + 64 <= HH);
    const int gy = y0 + wave * 16 + m;

    f32x4 acc5[5][2];
    const f32x4 zz = {0.f, 0.f, 0.f, 0.f};
    #pragma unroll
    for (int ch = 0; ch < 5; ++ch) { acc5[ch][0] = zz; acc5[ch][1] = zz; }

    #pragma unroll
    for (int ks = 0; ks < 2; ++ks) {
        const int cx = x0 + ks * 32 + q * 8;
        float a[8], b[8];
        if (interior) {
            const float* pa = inp + gy * WW + cx;   // 16B-aligned (x0 = 32tx-12)
            const float* pb = tgp + gy * WW + cx;
            float4 va0 = ((const float4*)pa)[0], va1 = ((const float4*)pa)[1];
            float4 vb0 = ((const float4*)pb)[0], vb1 = ((const float4*)pb)[1];
            a[0] = va0.x; a[1] = va0.y; a[2] = va0.z; a[3] = va0.w;
            a[4] = va1.x; a[5] = va1.y; a[6] = va1.z; a[7] = va1.w;
            b[0] = vb0.x; b[1] = vb0.y; b[2] = vb0.z; b[3] = vb0.w;
            b[4] = vb1.x; b[5] = vb1.y; b[6] = vb1.z; b[7] = vb1.w;
        } else {
            const int  gyc = min(max(gy, 0), HH - 1);
            const bool oky = ((unsigned)gy < (unsigned)HH);
            const float* ra = inp + gyc * WW;
            const float* rb = tgp + gyc * WW;
            #pragma unroll
            for (int i = 0; i < 8; ++i) {
                int gx = cx + i;
                int gxc = min(max(gx, 0), WW - 1);
                bool ok = oky && ((unsigned)gx < (unsigned)WW);
                float va = ra[gxc], vb = rb[gxc];
                a[i] = ok ? va : 0.f;
                b[i] = ok ? vb : 0.f;
            }
        }
        uint4 ua, ub, uaa, ubb, uab;
        ua.x  = cvtpk(a[0], a[1]);           ua.y  = cvtpk(a[2], a[3]);
        ua.z  = cvtpk(a[4], a[5]);           ua.w  = cvtpk(a[6], a[7]);
        ub.x  = cvtpk(b[0], b[1]);           ub.y  = cvtpk(b[2], b[3]);
        ub.z  = cvtpk(b[4], b[5]);           ub.w  = cvtpk(b[6], b[7]);
        uaa.x = cvtpk(a[0]*a[0], a[1]*a[1]); uaa.y = cvtpk(a[2]*a[2], a[3]*a[3]);
        uaa.z = cvtpk(a[4]*a[4], a[5]*a[5]); uaa.w = cvtpk(a[6]*a[6], a[7]*a[7]);
        ubb.x = cvtpk(b[0]*b[0], b[1]*b[1]); ubb.y = cvtpk(b[2]*b[2], b[3]*b[3]);
        ubb.z = cvtpk(b[4]*b[4], b[5]*b[5]); ubb.w = cvtpk(b[6]*b[6], b[7]*b[7]);
        uab.x = cvtpk(a[0]*b[0], a[1]*b[1]); uab.y = cvtpk(a[2]*b[2], a[3]*b[3]);
        uab.z = cvtpk(a[4]*b[4], a[5]*b[5]); uab.w = cvtpk(a[6]*b[6], a[7]*b[7]);

        #pragma unroll
        for (int nc = 0; nc < 2; ++nc) {
            const int gr = nc * 16 + m;
            uint4 gf = *(const uint4*)&lds[G_O + gr * 64 + SWZ(gr, ks * 32 + q * 8)];
            acc5[0][nc] = mfma16(ua,  gf, acc5[0][nc]);
            acc5[1][nc] = mfma16(ub,  gf, acc5[1][nc]);
            acc5[2][nc] = mfma16(uaa, gf, acc5[2][nc]);
            acc5[3][nc] = mfma16(ubb, gf, acc5[3][nc]);
            acc5[4][nc] = mfma16(uab, gf, acc5[4][nc]);
        }
    }
    // D frag: col = lane&15 (+nc*16), row = q*4 + reg (+wave*16). hbT[ch][col][row], bf16.
    // Waves 0..3 cover rows 0..63 => every hb row is written (finite junk on 0,55..63).
    #pragma unroll
    for (int ch = 0; ch < 5; ++ch)
        #pragma unroll
        for (int nc = 0; nc < 2; ++nc) {
            f32x4 a = acc5[ch][nc];
            uint2 pk;
            pk.x = cvtpk(a[0], a[1]);
            pk.y = cvtpk(a[2], a[3]);
            const int col = nc * 16 + m;
            const int rb = wave * 16 + q * 4;
            *(uint2*)&lds[HB_O + ch * HB_CH + col * 64 + SWZ(col, rb)] = pk;
        }
    __syncthreads();

    // ---- v-pass (MFMA): wave = output quadrant (mrow, nc2) ----
    // out[r][c] = sum_k G[r][k] * hb[k][c]; junk hb rows hit G zeros.
    const int mrow = wave >> 1, nc2 = wave & 1;
    f32x4 av[5];
    #pragma unroll
    for (int ch = 0; ch < 5; ++ch) av[ch] = zz;

    #pragma unroll
    for (int ks = 0; ks < 2; ++ks) {
        const int ar = mrow * 16 + m;
        uint4 ga = *(const uint4*)&lds[G_O + ar * 64 + SWZ(ar, ks * 32 + q * 8)];
        #pragma unroll
        for (int ch = 0; ch < 5; ++ch) {
            const int col = nc2 * 16 + m;
            uint4 ub = *(const uint4*)&lds[HB_O + ch * HB_CH + col * 64 + SWZ(col, ks * 32 + q * 8)];
            av[ch] = mfma16(ga, ub, av[ch]);
        }
    }

    // ---- SSIM map on 4 px/lane + reduction ----
    float lsum = 0.f;
    #pragma unroll
    for (int i = 0; i < 4; ++i) {
        float vx = av[0][i], vt = av[1][i];
        float vxx = av[2][i], vtt = av[3][i], vxt = av[4][i];
        float m1s = vx * vx, m2s = vt * vt, m12 = vx * vt;
        float s1 = vxx - m1s, s2 = vtt - m2s, s12 = vxt - m12;
        float num = (2.f * m12 + C1V) * (2.f * s12 + C2V);
        float den = (m1s + m2s + C1V) * (s1 + s2 + C2V);
        lsum += num * __builtin_amdgcn_rcpf(den);   // den > 0 always
    }
    #pragma unroll
    for (int off = 32; off > 0; off >>= 1)
        lsum += __shfl_down(lsum, off, 64);
    if (lane == 0) swsum[wave] = lsum;
    __syncthreads();
    if (tid == 0)
        partial[blk] = swsum[0] + swsum[1] + swsum[2] + swsum[3];  // plain store
}

__global__ __launch_bounds__(256) void ssim_final_kernel(
    const float* __restrict__ partial, float* __restrict__ out)
{
    __shared__ float swsum[4];
    const int tid = threadIdx.x;
    float s = 0.f;
    const float4* p4 = (const float4*)partial;
    for (int i = tid; i < NBLK / 4; i += 256) {
        float4 v = p4[i];
        s += (v.x + v.y) + (v.z + v.w);
    }
    #pragma unroll
    for (int off = 32; off > 0; off >>= 1)
        s += __shfl_down(s, off, 64);
    if ((tid & 63) == 0) swsum[tid >> 6] = s;
    __syncthreads();
    if (tid == 0)
        out[0] = 1.0f - (swsum[0] + swsum[1] + swsum[2] + swsum[3])
                        * (1.0f / ((float)NPLANES * HH * WW));
}

extern "C" void kernel_launch(void* const* d_in, const int* in_sizes, int n_in,
                              void* d_out, int out_size, void* d_ws, size_t ws_size,
                              hipStream_t stream) {
    const float* inp = (const float*)d_in[0];
    const float* tgt = (const float*)d_in[1];
    const float* wgt = (const float*)d_in[2];
    float* out = (float*)d_out;
    float* partial = (float*)d_ws;     // NBLK floats, fully overwritten each call

    ssim_main_kernel<<<NBLK, 256, 0, stream>>>(inp, tgt, wgt, partial);
    ssim_final_kernel<<<1, 256, 0, stream>>>(partial, out);
}

// Round 14
// 178.786 us; speedup vs baseline: 1.7798x; 1.5068x over previous
//
#include <hip/hip_runtime.h>
#include <hip/hip_bf16.h>

typedef float f32x4 __attribute__((ext_vector_type(4)));
typedef short bf16x8 __attribute__((ext_vector_type(8)));

#define HH 512
#define WW 512
#define NPLANES 48              // B*C = 16*3
#define KSIZE 23
#define NBLK (16 * 16 * NPLANES)
#define C1V 1.0e-4f             // 0.01^2
#define C2V 9.0e-4f             // 0.03^2

// LDS (ushort indices). Frame: tile*32 - 12 + k (k = frame row/col), so all
// global float4 loads are 16B-aligned. G[r][k] = g[k-1-r] for k-1-r in [0,23).
// Staged frame rows 0..54; h-pass M-rows 55..63 overflow-read exactly into the
// G region (SA_O + 55*72 == G_O), sB overflows into sA — finite bf16 always,
// and all junk is multiplied by exact zeros in G.
#define SB_O   0                // 55 rows * 72
#define SA_O   3960
#define G_O    7920             // 32 rows * 64, xor-swizzled
#define HB_O   9968             // 5 ch * 2048
#define HB_CH  2048
#define SPITCH 72
#define LDS_TOT 20208           // 40416 B -> 4 blocks/CU

// XOR bank swizzle for pitch-64 regions; preserves 16B blocks (bits 0..2).
#define SWZ(rho, k) ((k) ^ (((rho) & 7) << 3))

// pack two fp32 -> bf16 pair (lo = a, hi = b), RNE (v_cvt_pk_bf16_f32)
__device__ __forceinline__ unsigned cvtpk(float a, float b) {
    union { __hip_bfloat162 h; unsigned u; } cv;
    cv.h = __float22bfloat162_rn(make_float2(a, b));
    return cv.u;
}

// elementwise bf16 product of two bf16-pair dwords (fp32 exact mul, RNE round)
__device__ __forceinline__ unsigned bfmul2(unsigned a, unsigned b) {
    float al = __uint_as_float(a << 16), ah = __uint_as_float(a & 0xffff0000u);
    float bl = __uint_as_float(b << 16), bh = __uint_as_float(b & 0xffff0000u);
    return cvtpk(al * bl, ah * bh);
}

__device__ __forceinline__ uint4 bfmul4(uint4 a, uint4 b) {
    uint4 r;
    r.x = bfmul2(a.x, b.x); r.y = bfmul2(a.y, b.y);
    r.z = bfmul2(a.z, b.z); r.w = bfmul2(a.w, b.w);
    return r;
}

__device__ __forceinline__ f32x4 mfma16(uint4 a, uint4 b, f32x4 c) {
    union { uint4 u; bf16x8 h; } ua, ub;
    ua.u = a; ub.u = b;
    return __builtin_amdgcn_mfma_f32_16x16x32_bf16(ua.h, ub.h, c, 0, 0, 0);
}

// launch_bounds (256,4): VGPR cap 128 >= ~95-reg live set. (256,6) capped at
// ~85 and spilled 189 MB to scratch (round-12 post-mortem) — do not raise.
__global__ __launch_bounds__(256, 4) void ssim_main_kernel(
    const float* __restrict__ in, const float* __restrict__ tg,
    const float* __restrict__ w, float* __restrict__ partial)
{
    __shared__ __align__(16) unsigned short lds[LDS_TOT];
    __shared__ float swsum[4];

    const int tid = threadIdx.x;
    const int wave = tid >> 6, lane = tid & 63;
    const int m = lane & 15, q = lane >> 4;

    const int blk = blockIdx.x;
    const int plane = blk >> 8;
    const int t2 = blk & 255;
    const int x0 = (t2 & 15) * 32 - 12;   // 16B-aligned frame
    const int y0 = (t2 >> 4) * 32 - 12;
    const float* __restrict__ inp = in + (size_t)plane * (HH * WW);
    const float* __restrict__ tgp = tg + (size_t)plane * (HH * WW);

    const bool interior = (x0 >= 0) && (y0 >= 0) && (x0 + 64 <= WW) && (y0 + 55 <= HH);

    // ---- phase A: ISSUE staging loads first (interior fast path) ----
    // 55 rows x 8 col-groups(8) = 440 tasks; thread handles tid and tid+256.
    float4 La[2][2], Lb[2][2];
    if (interior) {
        #pragma unroll
        for (int it = 0; it < 2; ++it) {
            int t = tid + it * 256;
            if (t < 440) {
                int r = t >> 3, c8 = (t & 7) << 3;
                const float4* pa = (const float4*)(inp + (y0 + r) * WW + x0 + c8);
                const float4* pb = (const float4*)(tgp + (y0 + r) * WW + x0 + c8);
                La[it][0] = pa[0]; La[it][1] = pa[1];
                Lb[it][0] = pb[0]; Lb[it][1] = pb[1];
            }
        }
    }

    // ---- phase B (overlaps load latency): per-wave taps + G-build, no barrier ----
    // lanes 0..22: gv = 1D tap = row-sum of the separable normalized 2D kernel.
    float gv = 0.f;
    if (lane < KSIZE) {
        #pragma unroll
        for (int k = 0; k < KSIZE; ++k) gv += w[lane * KSIZE + k];
    }
    {   // wave builds G rows wave*8 .. wave*8+7 via intra-wave shfl
        unsigned* gw = (unsigned*)lds + (G_O >> 1);
        const int kd = lane & 31;              // dword col (k = 2kd, 2kd+1)
        const int rh = (lane >> 5) << 2;       // 0 or 4
        #pragma unroll
        for (int i = 0; i < 4; ++i) {
            int r = wave * 8 + rh + i;
            int d0 = 2 * kd - 1 - r;
            float g0 = __shfl(gv, d0 & 63, 64);
            float g1 = __shfl(gv, (d0 + 1) & 63, 64);
            g0 = ((unsigned)d0 < (unsigned)KSIZE) ? g0 : 0.f;
            g1 = ((unsigned)(d0 + 1) < (unsigned)KSIZE) ? g1 : 0.f;
            gw[r * 32 + (kd ^ ((r & 7) << 2))] = cvtpk(g0, g1);
        }
    }

    // ---- phase C: consume staging loads -> bf16 LDS ----
    if (interior) {
        #pragma unroll
        for (int it = 0; it < 2; ++it) {
            int t = tid + it * 256;
            if (t < 440) {
                int r = t >> 3, c8 = (t & 7) << 3;
                uint4 va, vb;
                va.x = cvtpk(La[it][0].x, La[it][0].y); va.y = cvtpk(La[it][0].z, La[it][0].w);
                va.z = cvtpk(La[it][1].x, La[it][1].y); va.w = cvtpk(La[it][1].z, La[it][1].w);
                vb.x = cvtpk(Lb[it][0].x, Lb[it][0].y); vb.y = cvtpk(Lb[it][0].z, Lb[it][0].w);
                vb.z = cvtpk(Lb[it][1].x, Lb[it][1].y); vb.w = cvtpk(Lb[it][1].z, Lb[it][1].w);
                *(uint4*)&lds[SA_O + r * SPITCH + c8] = va;
                *(uint4*)&lds[SB_O + r * SPITCH + c8] = vb;
            }
        }
    } else {
        unsigned* ldsw = (unsigned*)lds;
        for (int t = tid; t < 55 * 32; t += 256) {
            int r = t >> 5, cd = t & 31;
            int gy = y0 + r, gx = x0 + cd * 2;
            float a0 = 0.f, a1 = 0.f, b0 = 0.f, b1 = 0.f;
            if (gy >= 0 && gy < HH) {
                const float* ri = inp + gy * WW;
                const float* rt = tgp + gy * WW;
                if ((unsigned)gx < (unsigned)WW)       { a0 = ri[gx];     b0 = rt[gx]; }
                if ((unsigned)(gx + 1) < (unsigned)WW) { a1 = ri[gx + 1]; b1 = rt[gx + 1]; }
            }
            ldsw[(SA_O >> 1) + r * 36 + cd] = cvtpk(a0, a1);
            ldsw[(SB_O >> 1) + r * 36 + cd] = cvtpk(b0, b1);
        }
    }
    __syncthreads();   // one barrier covers staging + G

    // ---- h-pass (MFMA): wave = M-tile (frame rows wave*16..+15) ----
    f32x4 acc5[5][2];
    const f32x4 zz = {0.f, 0.f, 0.f, 0.f};
    #pragma unroll
    for (int ch = 0; ch < 5; ++ch) { acc5[ch][0] = zz; acc5[ch][1] = zz; }

    #pragma unroll
    for (int ks = 0; ks < 2; ++ks) {
        const int off = (wave * 16 + m) * SPITCH + ks * 32 + q * 8;
        uint4 ua = *(const uint4*)&lds[SA_O + off];
        uint4 ub = *(const uint4*)&lds[SB_O + off];
        uint4 uaa = bfmul4(ua, ua);
        uint4 ubb = bfmul4(ub, ub);
        uint4 uab = bfmul4(ua, ub);
        #pragma unroll
        for (int nc = 0; nc < 2; ++nc) {
            const int gr = nc * 16 + m;
            uint4 gf = *(const uint4*)&lds[G_O + gr * 64 + SWZ(gr, ks * 32 + q * 8)];
            acc5[0][nc] = mfma16(ua,  gf, acc5[0][nc]);
            acc5[1][nc] = mfma16(ub,  gf, acc5[1][nc]);
            acc5[2][nc] = mfma16(uaa, gf, acc5[2][nc]);
            acc5[3][nc] = mfma16(ubb, gf, acc5[3][nc]);
            acc5[4][nc] = mfma16(uab, gf, acc5[4][nc]);
        }
    }
    // D frag: col = lane&15 (+nc*16), row = q*4 + reg (+wave*16). hbT[ch][col][row].
    #pragma unroll
    for (int ch = 0; ch < 5; ++ch)
        #pragma unroll
        for (int nc = 0; nc < 2; ++nc) {
            f32x4 a = acc5[ch][nc];
            uint2 pk;
            pk.x = cvtpk(a[0], a[1]);
            pk.y = cvtpk(a[2], a[3]);
            const int col = nc * 16 + m;
            const int rb = wave * 16 + q * 4;
            *(uint2*)&lds[HB_O + ch * HB_CH + col * 64 + SWZ(col, rb)] = pk;
        }
    __syncthreads();

    // ---- v-pass (MFMA): wave = output quadrant (mrow, nc2) ----
    const int mrow = wave >> 1, nc2 = wave & 1;
    f32x4 av[5];
    #pragma unroll
    for (int ch = 0; ch < 5; ++ch) av[ch] = zz;

    #pragma unroll
    for (int ks = 0; ks < 2; ++ks) {
        const int ar = mrow * 16 + m;
        uint4 ga = *(const uint4*)&lds[G_O + ar * 64 + SWZ(ar, ks * 32 + q * 8)];
        #pragma unroll
        for (int ch = 0; ch < 5; ++ch) {
            const int col = nc2 * 16 + m;
            uint4 ub = *(const uint4*)&lds[HB_O + ch * HB_CH + col * 64 + SWZ(col, ks * 32 + q * 8)];
            av[ch] = mfma16(ga, ub, av[ch]);
        }
    }

    // ---- SSIM map on 4 px/lane + reduction ----
    float lsum = 0.f;
    #pragma unroll
    for (int i = 0; i < 4; ++i) {
        float vx = av[0][i], vt = av[1][i];
        float vxx = av[2][i], vtt = av[3][i], vxt = av[4][i];
        float m1s = vx * vx, m2s = vt * vt, m12 = vx * vt;
        float s1 = vxx - m1s, s2 = vtt - m2s, s12 = vxt - m12;
        float num = (2.f * m12 + C1V) * (2.f * s12 + C2V);
        float den = (m1s + m2s + C1V) * (s1 + s2 + C2V);
        lsum += num * __builtin_amdgcn_rcpf(den);   // den > 0 always
    }
    #pragma unroll
    for (int off = 32; off > 0; off >>= 1)
        lsum += __shfl_down(lsum, off, 64);
    if (lane == 0) swsum[wave] = lsum;
    __syncthreads();
    if (tid == 0)
        partial[blk] = swsum[0] + swsum[1] + swsum[2] + swsum[3];  // plain store
}

__global__ __launch_bounds__(256) void ssim_final_kernel(
    const float* __restrict__ partial, float* __restrict__ out)
{
    __shared__ float swsum[4];
    const int tid = threadIdx.x;
    float s = 0.f;
    const float4* p4 = (const float4*)partial;
    for (int i = tid; i < NBLK / 4; i += 256) {
        float4 v = p4[i];
        s += (v.x + v.y) + (v.z + v.w);
    }
    #pragma unroll
    for (int off = 32; off > 0; off >>= 1)
        s += __shfl_down(s, off, 64);
    if ((tid & 63) == 0) swsum[tid >> 6] = s;
    __syncthreads();
    if (tid == 0)
        out[0] = 1.0f - (swsum[0] + swsum[1] + swsum[2] + swsum[3])
                        * (1.0f / ((float)NPLANES * HH * WW));
}

extern "C" void kernel_launch(void* const* d_in, const int* in_sizes, int n_in,
                              void* d_out, int out_size, void* d_ws, size_t ws_size,
                              hipStream_t stream) {
    const float* inp = (const float*)d_in[0];
    const float* tgt = (const float*)d_in[1];
    const float* wgt = (const float*)d_in[2];
    float* out = (float*)d_out;
    float* partial = (float*)d_ws;     // NBLK floats, fully overwritten each call

    ssim_main_kernel<<<NBLK, 256, 0, stream>>>(inp, tgt, wgt, partial);
    ssim_final_kernel<<<1, 256, 0, stream>>>(partial, out);
}